// Round 4
// baseline (1096.738 us; speedup 1.0000x reference)
//
#include <hip/hip_runtime.h>
#include <hip/hip_bf16.h>

// Windowed 3D attention transformer block, MI355X bf16-MFMA implementation.
// Residual stream fp32; GEMM/attention compute bf16 in, fp32 accumulate.
// R6: T4 counted-vmcnt pipeline in gemm_bt. Depth-2 staging (tiles t, t+1 in
//     flight), top-of-tile s_waitcnt vmcnt(8) (NOT 0) + raw s_barrier, issue
//     of tile t+2 after the bottom barrier. Loads cross two barriers in
//     flight; the only vmcnt(0) is at the last tile. Tile body unchanged
//     from R4 (compiler-scheduled ds_read/MFMA + setprio). sched_barrier(0)
//     pins the sync boundaries against compiler code motion.

typedef __attribute__((ext_vector_type(4))) short short4v;
typedef __attribute__((ext_vector_type(8))) short short8v;
typedef __attribute__((ext_vector_type(4))) float f32x4;

__device__ __forceinline__ unsigned short f2bf(float f) {
  unsigned u = __float_as_uint(f);
  u += 0x7fffu + ((u >> 16) & 1u);   // RNE; inputs finite
  return (unsigned short)(u >> 16);
}

// branch-free erf, Abramowitz-Stegun 7.1.26, |err| <= 1.5e-7
__device__ __forceinline__ float erf_fast(float x) {
  float ax = fabsf(x);
  float y = 1.0f + 0.3275911f * ax;
  float t;
  asm("v_rcp_f32 %0, %1" : "=v"(t) : "v"(y));           // ~1ulp, fine at 1e-7 scale
  float p = t * (0.254829592f +
            t * (-0.284496736f +
            t * (1.421413741f +
            t * (-1.453152027f +
            t * 1.061405429f))));
  float e = __expf(-ax * ax);
  float r = 1.0f - p * e;
  return copysignf(r, x);
}

// async 16B global->LDS DMA; LDS dest = wave-uniform base + lane*16
__device__ __forceinline__ void gload_lds16(const unsigned short* g, unsigned short* l) {
  __builtin_amdgcn_global_load_lds(
      (const __attribute__((address_space(1))) unsigned int*)g,
      (__attribute__((address_space(3))) unsigned int*)l, 16, 0, 0);
}

// ---------------- weight prep (all 4 weights, one launch) ------------------
// wt element layout: [qkv 512x1536 ->786432][proj ->262144][w1 ->1048576][w2 ->1048576]
__global__ __launch_bounds__(256)
void wprep_all(const float* __restrict__ qkv_w, const float* __restrict__ proj_w,
               const float* __restrict__ w1, const float* __restrict__ w2,
               unsigned short* __restrict__ wt) {
  int idx = blockIdx.x * 256 + threadIdx.x;
  const float* w; int kbits, N, base;
  if (idx < 786432)       { w = qkv_w;  kbits = 9;  N = 1536; base = 0; }
  else if (idx < 1048576) { w = proj_w; kbits = 9;  N = 512;  base = 786432; }
  else if (idx < 2097152) { w = w1;     kbits = 9;  N = 2048; base = 1048576; }
  else                    { w = w2;     kbits = 11; N = 512;  base = 2097152; }
  int li = idx - base;
  int K = 1 << kbits;
  int n = li >> kbits, kk = li & (K - 1);
  wt[idx] = f2bf(w[(long)kk * N + n]);
}

// ---------------- LayerNorm (one wave per 512-elem row) --------------------
__global__ __launch_bounds__(256)
void ln_kernel(const float* __restrict__ src, const float* __restrict__ g,
               const float* __restrict__ bb, unsigned short* __restrict__ dst,
               const int gather) {
  const int lane = threadIdx.x & 63;
  const int row = blockIdx.x * 4 + (threadIdx.x >> 6);
  long srow;
  if (gather) {
    int n = row & 63, win = row >> 6;
    int w0 = win & 7, h0 = (win >> 3) & 7, d0 = (win >> 6) & 7, b2 = win >> 9;
    int dx = n & 3, dy = (n >> 2) & 3, dz = n >> 4;
    int od = (d0 * 4 + dz + 2) & 31, oh = (h0 * 4 + dy + 2) & 31, ow = (w0 * 4 + dx + 2) & 31;
    srow = (((long)b2 * 32 + od) * 32 + oh) * 32 + ow;
  } else {
    srow = row;
  }
  const float4* sp = (const float4*)(src + srow * 512);
  float4 x0 = sp[lane], x1 = sp[lane + 64];
  float sum = x0.x + x0.y + x0.z + x0.w + x1.x + x1.y + x1.z + x1.w;
  float sq  = x0.x*x0.x + x0.y*x0.y + x0.z*x0.z + x0.w*x0.w
            + x1.x*x1.x + x1.y*x1.y + x1.z*x1.z + x1.w*x1.w;
#pragma unroll
  for (int off = 1; off < 64; off <<= 1) {
    sum += __shfl_xor(sum, off, 64);
    sq  += __shfl_xor(sq, off, 64);
  }
  float mean = sum * (1.0f / 512.0f);
  float var  = sq * (1.0f / 512.0f) - mean * mean;
  float rstd = rsqrtf(var + 1e-5f);
  float4 g0 = ((const float4*)g)[lane], g1 = ((const float4*)g)[lane + 64];
  float4 b0 = ((const float4*)bb)[lane], b1v = ((const float4*)bb)[lane + 64];
  ushort4 o0, o1;
  o0.x = f2bf((x0.x - mean) * rstd * g0.x + b0.x);
  o0.y = f2bf((x0.y - mean) * rstd * g0.y + b0.y);
  o0.z = f2bf((x0.z - mean) * rstd * g0.z + b0.z);
  o0.w = f2bf((x0.w - mean) * rstd * g0.w + b0.w);
  o1.x = f2bf((x1.x - mean) * rstd * g1.x + b1v.x);
  o1.y = f2bf((x1.y - mean) * rstd * g1.y + b1v.y);
  o1.z = f2bf((x1.z - mean) * rstd * g1.z + b1v.z);
  o1.w = f2bf((x1.w - mean) * rstd * g1.w + b1v.w);
  *(ushort4*)(dst + (long)row * 512 + lane * 4) = o0;
  *(ushort4*)(dst + (long)row * 512 + 256 + lane * 4) = o1;
}

// ---------------- GEMM: C[M,N] = A[M,K](bf16) * Bt[N,K]^T + bias ----------
// 256x256 block tile, BK=64 double-buffered, 8 waves (2M x 4N), per-wave
// 128x64 output (8x4 16x16x32 MFMA fragments).
// LDS rows are 8 chunks of 16B; chunk slot c of row r holds global chunk
// c ^ (r&7)  (linear LDS dest for global_load_lds, pre-swizzled source).
// Sync structure (T4): per wave 8 gload_lds/tile; tiles t and t+1 in flight;
// top of tile t waits vmcnt(8) (t's loads only) + s_barrier; bottom barrier
// frees buf[cur], then tile t+2 is issued into it. No vmcnt(0) until the
// final tile.
template <int EPI>
__global__ __launch_bounds__(512, 2)
void gemm_bt(const unsigned short* __restrict__ A,
             const unsigned short* __restrict__ Bt,
             const float* __restrict__ bias, int K,
             void* __restrict__ out0,
             unsigned short* __restrict__ out1,
             unsigned short* __restrict__ out2,
             const float* __restrict__ res) {
  __shared__ unsigned short As[2][256 * 64];
  __shared__ unsigned short Bs[2][256 * 64];
  const int tid = threadIdx.x;
  const int lane = tid & 63;
  const int wv = tid >> 6;           // 0..7
  const int wm = wv >> 2;            // 0..1  (M half)
  const int wn = wv & 3;             // 0..3  (N quarter)
  const int quad = lane >> 4;
  const int l15 = lane & 15;

  // T1: bijective XCD swizzle (all grids are multiples of 8 blocks)
  const int gx = gridDim.x;
  const int nwg = gx * gridDim.y;
  const int bid = blockIdx.y * gx + blockIdx.x;
  const int cpx = nwg >> 3;
  const int wg2 = (bid & 7) * cpx + (bid >> 3);
  const int bx = wg2 % gx;
  const int by = wg2 / gx;
  const long row0 = (long)by * 256;
  const long col0 = (long)bx * 256;

  f32x4 acc[8][4] = {};

  // staging geometry: round j, wave wv, lane l covers LDS chunk
  // (j*8+wv)*64 + l  ->  row r = j*64 + wv*8 + (l>>3), chunk slot l&7,
  // which must hold global chunk (l&7) ^ (r&7) = (l&7) ^ (l>>3).
  const int srow = wv * 8 + (lane >> 3);
  const int scg  = (lane & 7) ^ (lane >> 3);
  const unsigned short* gA = A  + (row0 + srow) * K + scg * 8;
  const unsigned short* gB = Bt + (col0 + srow) * K + scg * 8;
  const long jmp = 64L * K;          // elements per 64-row staging round
  const int ldst = wv * 512;         // ushort offset; + j*4096 per round

#define STAGE_A(buf, koff) do {                                         \
    _Pragma("unroll")                                                   \
    for (int j = 0; j < 4; ++j)                                         \
      gload_lds16(gA + (koff) + j * jmp, &As[buf][ldst + j * 4096]);    \
  } while (0)
#define STAGE_B(buf, koff) do {                                         \
    _Pragma("unroll")                                                   \
    for (int j = 0; j < 4; ++j)                                         \
      gload_lds16(gB + (koff) + j * jmp, &Bs[buf][ldst + j * 4096]);    \
  } while (0)

  // fragment read bases: row = (wm*128|wn*64) + frag*16 + l15, global chunk
  // quad + 4*ks, LDS chunk = (quad+4*ks) ^ (row&7); row&7 == l15&7 here.
  const int co0 = ((quad)     ^ (l15 & 7)) * 8;
  const int co1 = ((quad + 4) ^ (l15 & 7)) * 8;
  const int aB0 = (wm * 128 + l15) * 64 + co0;
  const int aB1 = (wm * 128 + l15) * 64 + co1;
  const int bB0 = (wn * 64 + l15) * 64 + co0;
  const int bB1 = (wn * 64 + l15) * 64 + co1;

  const int nk = K >> 6;             // >= 8 at all call sites
  // prologue: tiles 0 and 1 in flight (8 gloads each per wave, in order)
  STAGE_A(0, 0);
  STAGE_B(0, 0);
  STAGE_A(1, 64);
  STAGE_B(1, 64);

  for (int t = 0; t < nk; ++t) {
    const int cur = t & 1;
    const unsigned short* Ac = As[cur];
    const unsigned short* Bc = Bs[cur];
    // ---- top-of-tile sync: wait THIS tile's loads only (t+1 stays in flight)
    if (t + 1 < nk) asm volatile("s_waitcnt vmcnt(8)" ::: "memory");
    else            asm volatile("s_waitcnt vmcnt(0)" ::: "memory");
    __builtin_amdgcn_s_barrier();
    __builtin_amdgcn_sched_barrier(0);

    // ---- tile body: compiler-scheduled ds_read / MFMA interleave
    short8v bf0[4], bf1[4];
#pragma unroll
    for (int nt = 0; nt < 4; ++nt) {
      bf0[nt] = *(const short8v*)&Bc[bB0 + nt * 1024];
      bf1[nt] = *(const short8v*)&Bc[bB1 + nt * 1024];
    }
#pragma unroll
    for (int mh = 0; mh < 2; ++mh) {
      short8v af0[4], af1[4];
#pragma unroll
      for (int i = 0; i < 4; ++i) {
        af0[i] = *(const short8v*)&Ac[aB0 + (mh * 4 + i) * 1024];
        af1[i] = *(const short8v*)&Ac[aB1 + (mh * 4 + i) * 1024];
      }
      __builtin_amdgcn_s_setprio(1);
#pragma unroll
      for (int i = 0; i < 4; ++i)
#pragma unroll
        for (int nt = 0; nt < 4; ++nt)
          acc[mh * 4 + i][nt] = __builtin_amdgcn_mfma_f32_16x16x32_bf16(
              af0[i], bf0[nt], acc[mh * 4 + i][nt], 0, 0, 0);
#pragma unroll
      for (int i = 0; i < 4; ++i)
#pragma unroll
        for (int nt = 0; nt < 4; ++nt)
          acc[mh * 4 + i][nt] = __builtin_amdgcn_mfma_f32_16x16x32_bf16(
              af1[i], bf1[nt], acc[mh * 4 + i][nt], 0, 0, 0);
      __builtin_amdgcn_s_setprio(0);
    }

    // ---- bottom-of-tile sync: all waves done reading buf[cur]; then refill
    __builtin_amdgcn_sched_barrier(0);
    asm volatile("s_waitcnt lgkmcnt(0)" ::: "memory");
    __builtin_amdgcn_s_barrier();
    __builtin_amdgcn_sched_barrier(0);
    if (t + 2 < nk) {                // tile t+2 into the buffer just freed
      const int kn2 = (t + 2) << 6;
      STAGE_A(cur, kn2);
      STAGE_B(cur, kn2);
    }
  }
#undef STAGE_A
#undef STAGE_B

#pragma unroll
  for (int mt = 0; mt < 8; ++mt) {
#pragma unroll
    for (int nt = 0; nt < 4; ++nt) {
#pragma unroll
      for (int r = 0; r < 4; ++r) {
        const long gr = row0 + wm * 128 + mt * 16 + quad * 4 + r;
        const long gc = col0 + wn * 64 + nt * 16 + l15;
        float val = acc[mt][nt][r] + bias[gc];
        if (EPI == 0) {
          int which = (int)(gc >> 9), rem = (int)gc & 511;
          int head = rem >> 6, hd = rem & 63;
          long win = gr >> 6, n = gr & 63;
          long base = (win * 8 + head) * 4096;
          unsigned short bv = f2bf(val);
          if (which == 0)      ((unsigned short*)out0)[base + n * 64 + hd] = bv;
          else if (which == 1) out1[base + n * 64 + hd] = bv;
          else                 out2[base + hd * 64 + n] = bv;   // v transposed
        } else if (EPI == 1) {
          int win = (int)(gr >> 6), n = (int)gr & 63;
          int w0 = win & 7, h0 = (win >> 3) & 7, d0 = (win >> 6) & 7, b2 = win >> 9;
          int dx = n & 3, dy = (n >> 2) & 3, dz = n >> 4;
          int od = (d0 * 4 + dz + 2) & 31, oh = (h0 * 4 + dy + 2) & 31, ow = (w0 * 4 + dx + 2) & 31;
          long addr = ((((long)b2 * 32 + od) * 32 + oh) * 32 + ow) * 512 + gc;
          ((float*)out0)[addr] = res[addr] + val;
        } else if (EPI == 2) {
          float ge = 0.5f * val * (1.0f + erf_fast(val * 0.70710678118654752f));
          ((unsigned short*)out0)[gr * 2048 + gc] = f2bf(ge);
        } else {
          long addr = gr * 512 + gc;
          ((float*)out0)[addr] = res[addr] + val;
        }
      }
    }
  }
}

// ---------------- attention: one wave per (window, head) -------------------
__global__ __launch_bounds__(256)
void attn_kernel(const unsigned short* __restrict__ q,
                 const unsigned short* __restrict__ k,
                 const unsigned short* __restrict__ vt,
                 unsigned short* __restrict__ out) {
  __shared__ unsigned short Ps[4][64 * 72];
  const int lane = threadIdx.x & 63;
  const int wave = threadIdx.x >> 6;
  const int quad = lane >> 4;
  const int l15 = lane & 15;
  const int unit = blockIdx.x * 4 + wave;
  const int win = unit >> 3;
  const int head = unit & 7;
  const long base = (long)unit * 4096;

  f32x4 s[4][4] = {};
#pragma unroll
  for (int kk = 0; kk < 64; kk += 32) {
    short8v a[4], b[4];
#pragma unroll
    for (int t = 0; t < 4; ++t) {
      a[t] = *(const short8v*)(q + base + (t * 16 + l15) * 64 + kk + quad * 8);
      b[t] = *(const short8v*)(k + base + (t * 16 + l15) * 64 + kk + quad * 8);
    }
#pragma unroll
    for (int mt = 0; mt < 4; ++mt)
#pragma unroll
      for (int nt = 0; nt < 4; ++nt)
        s[mt][nt] = __builtin_amdgcn_mfma_f32_16x16x32_bf16(a[mt], b[nt], s[mt][nt], 0, 0, 0);
  }

  float lrow[4][4];
#pragma unroll
  for (int mt = 0; mt < 4; ++mt) {
#pragma unroll
    for (int r = 0; r < 4; ++r) {
      float v0 = s[mt][0][r] * 0.125f, v1 = s[mt][1][r] * 0.125f;
      float v2 = s[mt][2][r] * 0.125f, v3 = s[mt][3][r] * 0.125f;
      float mx = fmaxf(fmaxf(v0, v1), fmaxf(v2, v3));
#pragma unroll
      for (int off = 1; off < 16; off <<= 1) mx = fmaxf(mx, __shfl_xor(mx, off, 64));
      v0 = __expf(v0 - mx); v1 = __expf(v1 - mx);
      v2 = __expf(v2 - mx); v3 = __expf(v3 - mx);
      float sm = v0 + v1 + v2 + v3;
#pragma unroll
      for (int off = 1; off < 16; off <<= 1) sm += __shfl_xor(sm, off, 64);
      lrow[mt][r] = sm;
      int row = mt * 16 + quad * 4 + r;
      Ps[wave][row * 72 + 0 + l15]  = f2bf(v0);
      Ps[wave][row * 72 + 16 + l15] = f2bf(v1);
      Ps[wave][row * 72 + 32 + l15] = f2bf(v2);
      Ps[wave][row * 72 + 48 + l15] = f2bf(v3);
    }
  }
  __syncthreads();

  f32x4 o[4][4] = {};
#pragma unroll
  for (int kk = 0; kk < 64; kk += 32) {
    short8v a[4], b[4];
#pragma unroll
    for (int t = 0; t < 4; ++t) {
      a[t] = *(const short8v*)(&Ps[wave][(t * 16 + l15) * 72 + kk + quad * 8]);
      b[t] = *(const short8v*)(vt + base + (t * 16 + l15) * 64 + kk + quad * 8);
    }
#pragma unroll
    for (int mt = 0; mt < 4; ++mt)
#pragma unroll
      for (int nt = 0; nt < 4; ++nt)
        o[mt][nt] = __builtin_amdgcn_mfma_f32_16x16x32_bf16(a[mt], b[nt], o[mt][nt], 0, 0, 0);
  }

#pragma unroll
  for (int mt = 0; mt < 4; ++mt)
#pragma unroll
    for (int nt = 0; nt < 4; ++nt)
#pragma unroll
      for (int r = 0; r < 4; ++r) {
        int row = mt * 16 + quad * 4 + r;
        int col = nt * 16 + l15;
        float val = o[mt][nt][r] / lrow[mt][r];
        out[((long)win * 64 + row) * 512 + head * 64 + col] = f2bf(val);
      }
}

// ---------------- launch ---------------------------------------------------
extern "C" void kernel_launch(void* const* d_in, const int* in_sizes, int n_in,
                              void* d_out, int out_size, void* d_ws, size_t ws_size,
                              hipStream_t stream) {
  const float* x      = (const float*)d_in[0];
  const float* ln1_g  = (const float*)d_in[1];
  const float* ln1_b  = (const float*)d_in[2];
  const float* qkv_w  = (const float*)d_in[3];
  const float* qkv_b  = (const float*)d_in[4];
  const float* proj_w = (const float*)d_in[5];
  const float* proj_b = (const float*)d_in[6];
  const float* ln2_g  = (const float*)d_in[7];
  const float* ln2_b  = (const float*)d_in[8];
  const float* w1     = (const float*)d_in[9];
  const float* b1     = (const float*)d_in[10];
  const float* w2     = (const float*)d_in[11];
  const float* b2     = (const float*)d_in[12];

  // workspace layout (bytes); hid overlays attn_out+q+k+v (dead after proj)
  char* ws = (char*)d_ws;
  unsigned short* wt_all  = (unsigned short*)ws;
  unsigned short* wt_qkv  = (unsigned short*)(ws + 0);          // 1536x512 bf16
  unsigned short* wt_proj = (unsigned short*)(ws + 1572864);    // 512x512
  unsigned short* wt_1    = (unsigned short*)(ws + 2097152);    // 2048x512
  unsigned short* wt_2    = (unsigned short*)(ws + 4194304);    // 512x2048
  float*          xo      = (float*)(ws + 8388608);             // 128 MiB fp32
  unsigned short* h       = (unsigned short*)(ws + 142606336);  // 64 MiB bf16 (h, then h2)
  unsigned short* attno   = (unsigned short*)(ws + 209715200);  // 64 MiB
  unsigned short* qb      = (unsigned short*)(ws + 276824064);  // 64 MiB
  unsigned short* kb      = (unsigned short*)(ws + 343932928);  // 64 MiB
  unsigned short* vb      = (unsigned short*)(ws + 411041792);  // 64 MiB
  unsigned short* hid     = (unsigned short*)(ws + 209715200);  // 256 MiB overlay
  float* out = (float*)d_out;

  wprep_all<<<12288, 256, 0, stream>>>(qkv_w, proj_w, w1, w2, wt_all);

  ln_kernel<<<16384, 256, 0, stream>>>(x, ln1_g, ln1_b, h, 1);
  gemm_bt<0><<<dim3(6, 256), 512, 0, stream>>>(h, wt_qkv, qkv_b, 512, qb, kb, vb, nullptr);
  attn_kernel<<<2048, 256, 0, stream>>>(qb, kb, vb, attno);
  gemm_bt<1><<<dim3(2, 256), 512, 0, stream>>>(attno, wt_proj, proj_b, 512, xo, nullptr, nullptr, x);
  ln_kernel<<<16384, 256, 0, stream>>>(xo, ln2_g, ln2_b, h, 0);
  gemm_bt<2><<<dim3(8, 256), 512, 0, stream>>>(h, wt_1, b1, 512, hid, nullptr, nullptr, nullptr);
  gemm_bt<3><<<dim3(2, 256), 512, 0, stream>>>(hid, wt_2, b2, 2048, out, nullptr, nullptr, xo);
}

// Round 6
// 1071.453 us; speedup vs baseline: 1.0236x; 1.0236x over previous
//
#include <hip/hip_runtime.h>
#include <hip/hip_bf16.h>

// Windowed 3D attention transformer block, MI355X bf16-MFMA implementation.
// Residual stream fp32; GEMM/attention compute bf16 in, fp32 accumulate.
// R8 = R7 (m201-style schedule: K=32 sub-tiles, 4-slot LDS ring, 3 in
//     flight, counted vmcnt(8) per phase, one barrier per phase) with the
//     LDS chunk swizzle corrected to slot = quad ^ ((row>>1)&3): with 64 B
//     rows, XOR by (row&3) left bank_start repeating every 4 lanes (2-way
//     conflict in each 8-lane b128 group); (row>>1)&3 makes lanes 0..7
//     cover all 32 banks exactly once. Prior round's bench was an infra
//     failure (same error as R2, which passed on resubmission).

typedef __attribute__((ext_vector_type(4))) short short4v;
typedef __attribute__((ext_vector_type(8))) short short8v;
typedef __attribute__((ext_vector_type(4))) float f32x4;

__device__ __forceinline__ unsigned short f2bf(float f) {
  unsigned u = __float_as_uint(f);
  u += 0x7fffu + ((u >> 16) & 1u);   // RNE; inputs finite
  return (unsigned short)(u >> 16);
}

// branch-free erf, Abramowitz-Stegun 7.1.26, |err| <= 1.5e-7
__device__ __forceinline__ float erf_fast(float x) {
  float ax = fabsf(x);
  float y = 1.0f + 0.3275911f * ax;
  float t;
  asm("v_rcp_f32 %0, %1" : "=v"(t) : "v"(y));           // ~1ulp, fine at 1e-7 scale
  float p = t * (0.254829592f +
            t * (-0.284496736f +
            t * (1.421413741f +
            t * (-1.453152027f +
            t * 1.061405429f))));
  float e = __expf(-ax * ax);
  float r = 1.0f - p * e;
  return copysignf(r, x);
}

// async 16B global->LDS DMA; LDS dest = wave-uniform base + lane*16
__device__ __forceinline__ void gload_lds16(const unsigned short* g, unsigned short* l) {
  __builtin_amdgcn_global_load_lds(
      (const __attribute__((address_space(1))) unsigned int*)g,
      (__attribute__((address_space(3))) unsigned int*)l, 16, 0, 0);
}

// ---------------- weight prep (all 4 weights, one launch) ------------------
// wt element layout: [qkv 512x1536 ->786432][proj ->262144][w1 ->1048576][w2 ->1048576]
__global__ __launch_bounds__(256)
void wprep_all(const float* __restrict__ qkv_w, const float* __restrict__ proj_w,
               const float* __restrict__ w1, const float* __restrict__ w2,
               unsigned short* __restrict__ wt) {
  int idx = blockIdx.x * 256 + threadIdx.x;
  const float* w; int kbits, N, base;
  if (idx < 786432)       { w = qkv_w;  kbits = 9;  N = 1536; base = 0; }
  else if (idx < 1048576) { w = proj_w; kbits = 9;  N = 512;  base = 786432; }
  else if (idx < 2097152) { w = w1;     kbits = 9;  N = 2048; base = 1048576; }
  else                    { w = w2;     kbits = 11; N = 512;  base = 2097152; }
  int li = idx - base;
  int K = 1 << kbits;
  int n = li >> kbits, kk = li & (K - 1);
  wt[idx] = f2bf(w[(long)kk * N + n]);
}

// ---------------- LayerNorm (one wave per 512-elem row) --------------------
__global__ __launch_bounds__(256)
void ln_kernel(const float* __restrict__ src, const float* __restrict__ g,
               const float* __restrict__ bb, unsigned short* __restrict__ dst,
               const int gather) {
  const int lane = threadIdx.x & 63;
  const int row = blockIdx.x * 4 + (threadIdx.x >> 6);
  long srow;
  if (gather) {
    int n = row & 63, win = row >> 6;
    int w0 = win & 7, h0 = (win >> 3) & 7, d0 = (win >> 6) & 7, b2 = win >> 9;
    int dx = n & 3, dy = (n >> 2) & 3, dz = n >> 4;
    int od = (d0 * 4 + dz + 2) & 31, oh = (h0 * 4 + dy + 2) & 31, ow = (w0 * 4 + dx + 2) & 31;
    srow = (((long)b2 * 32 + od) * 32 + oh) * 32 + ow;
  } else {
    srow = row;
  }
  const float4* sp = (const float4*)(src + srow * 512);
  float4 x0 = sp[lane], x1 = sp[lane + 64];
  float sum = x0.x + x0.y + x0.z + x0.w + x1.x + x1.y + x1.z + x1.w;
  float sq  = x0.x*x0.x + x0.y*x0.y + x0.z*x0.z + x0.w*x0.w
            + x1.x*x1.x + x1.y*x1.y + x1.z*x1.z + x1.w*x1.w;
#pragma unroll
  for (int off = 1; off < 64; off <<= 1) {
    sum += __shfl_xor(sum, off, 64);
    sq  += __shfl_xor(sq, off, 64);
  }
  float mean = sum * (1.0f / 512.0f);
  float var  = sq * (1.0f / 512.0f) - mean * mean;
  float rstd = rsqrtf(var + 1e-5f);
  float4 g0 = ((const float4*)g)[lane], g1 = ((const float4*)g)[lane + 64];
  float4 b0 = ((const float4*)bb)[lane], b1v = ((const float4*)bb)[lane + 64];
  ushort4 o0, o1;
  o0.x = f2bf((x0.x - mean) * rstd * g0.x + b0.x);
  o0.y = f2bf((x0.y - mean) * rstd * g0.y + b0.y);
  o0.z = f2bf((x0.z - mean) * rstd * g0.z + b0.z);
  o0.w = f2bf((x0.w - mean) * rstd * g0.w + b0.w);
  o1.x = f2bf((x1.x - mean) * rstd * g1.x + b1v.x);
  o1.y = f2bf((x1.y - mean) * rstd * g1.y + b1v.y);
  o1.z = f2bf((x1.z - mean) * rstd * g1.z + b1v.z);
  o1.w = f2bf((x1.w - mean) * rstd * g1.w + b1v.w);
  *(ushort4*)(dst + (long)row * 512 + lane * 4) = o0;
  *(ushort4*)(dst + (long)row * 512 + 256 + lane * 4) = o1;
}

// ---------------- GEMM: C[M,N] = A[M,K](bf16) * Bt[N,K]^T + bias ----------
// 256x256 block tile, 8 waves (2M x 4N), per-wave 128x64 output.
// K is processed in K=32 sub-tiles through a 4-slot LDS ring:
//   SB[slot][A|B][256 rows][32 elems]  (row = 64 B = 4 chunks of 16 B)
// Chunk swizzle: LDS slot s of row r holds global chunk s ^ ((r>>1)&3);
// staging keeps LDS linear (lane*16) and pre-swizzles the GLOBAL source;
// fragment reads use slot = quad ^ ((r>>1)&3). Lanes 0..7 of a b128 read
// then cover all 32 banks exactly once -> conflict-free.
// Phase u (one per sub-tile): vmcnt(8) [subs u+1,u+2 stay in flight] ->
// s_barrier -> stage sub u+3 into slot (u-1)&3 (safe: all waves passed the
// barrier with their reads of u-1 retired) -> reads+MFMA. Tail: vmcnt(4),
// then vmcnt(0). sched_barrier(0) pins issue order per phase.
template <int EPI>
__global__ __launch_bounds__(512, 2)
void gemm_bt(const unsigned short* __restrict__ A,
             const unsigned short* __restrict__ Bt,
             const float* __restrict__ bias, int K,
             void* __restrict__ out0,
             unsigned short* __restrict__ out1,
             unsigned short* __restrict__ out2,
             const float* __restrict__ res) {
  __shared__ unsigned short SB[4][2][8192];   // 4 ring slots x {A,B} x 256x32
  const int tid = threadIdx.x;
  const int lane = tid & 63;
  const int wv = tid >> 6;           // 0..7
  const int wm = wv >> 2;            // 0..1  (M half)
  const int wn = wv & 3;             // 0..3  (N quarter)
  const int quad = lane >> 4;
  const int l15 = lane & 15;

  // T1: bijective XCD swizzle (all grids are multiples of 8 blocks)
  const int gx = gridDim.x;
  const int nwg = gx * gridDim.y;
  const int bid = blockIdx.y * gx + blockIdx.x;
  const int cpx = nwg >> 3;
  const int wg2 = (bid & 7) * cpx + (bid >> 3);
  const int bx = wg2 % gx;
  const int by = wg2 / gx;
  const long row0 = (long)by * 256;
  const long col0 = (long)bx * 256;

  f32x4 acc[8][4] = {};

  // staging: per sub-tile each thread issues 4 gloads (A j0/j1, B j0/j1).
  // lane l covers row srow = wv*16 + (l>>2) (j adds 128), LDS chunk slot
  // l&3, holding global chunk (l&3) ^ ((srow>>1)&3) = (l&3) ^ ((l>>3)&3).
  const int srow = wv * 16 + (lane >> 2);
  const int scg  = (lane & 3) ^ ((lane >> 3) & 3);
  const unsigned short* gA0 = A  + (row0 + srow) * K + scg * 8;
  const unsigned short* gB0 = Bt + (col0 + srow) * K + scg * 8;
  const long j1 = 128L * K;          // +128 rows ((r+128)>>1 & 3 unchanged)
  const int lds0 = srow * 32 + (lane & 3) * 8;   // ushort idx; +4096 for j1

#define STAGE(v) do {                                              \
    const int q_ = (v) & 3; const long ko_ = (long)(v) * 32;       \
    gload_lds16(gA0 + ko_,      &SB[q_][0][lds0]);                 \
    gload_lds16(gA0 + ko_ + j1, &SB[q_][0][lds0 + 4096]);          \
    gload_lds16(gB0 + ko_,      &SB[q_][1][lds0]);                 \
    gload_lds16(gB0 + ko_ + j1, &SB[q_][1][lds0 + 4096]);          \
  } while (0)

  // fragment read bases: row ra = wm*128 + frag*16 + l15 (A),
  // rb = wn*64 + frag*16 + l15 (B); (row>>1)&3 == (l15>>1)&3 for both.
  const int slot = (quad ^ ((l15 >> 1) & 3)) * 8;
  const int aoff = (wm * 128 + l15) * 32 + slot;
  const int boff = (wn * 64  + l15) * 32 + slot;

  const int nsub = K >> 5;           // K=32 sub-tiles; >= 16 at all call sites
  STAGE(0); STAGE(1); STAGE(2);      // 3 sub-tiles in flight (12 loads/thread)

  for (int u = 0; u < nsub; ++u) {
    // counted wait: sub u resident; u+1, u+2 stay in flight (4 loads each)
    if (u < nsub - 2)       asm volatile("s_waitcnt vmcnt(8)" ::: "memory");
    else if (u == nsub - 2) asm volatile("s_waitcnt vmcnt(4)" ::: "memory");
    else                    asm volatile("s_waitcnt vmcnt(0)" ::: "memory");
    __builtin_amdgcn_s_barrier();
    __builtin_amdgcn_sched_barrier(0);
    if (u + 3 < nsub) STAGE(u + 3);  // into slot (u-1)&3, freed by the barrier

    const unsigned short* Au = &SB[u & 3][0][0];
    const unsigned short* Bu = &SB[u & 3][1][0];
    short8v bf[4];
#pragma unroll
    for (int nt = 0; nt < 4; ++nt) bf[nt] = *(const short8v*)&Bu[boff + nt * 512];
#pragma unroll
    for (int mh = 0; mh < 2; ++mh) {
      short8v af[4];
#pragma unroll
      for (int i = 0; i < 4; ++i) af[i] = *(const short8v*)&Au[aoff + (mh * 4 + i) * 512];
      __builtin_amdgcn_s_setprio(1);
#pragma unroll
      for (int i = 0; i < 4; ++i)
#pragma unroll
        for (int nt = 0; nt < 4; ++nt)
          acc[mh * 4 + i][nt] = __builtin_amdgcn_mfma_f32_16x16x32_bf16(
              af[i], bf[nt], acc[mh * 4 + i][nt], 0, 0, 0);
      __builtin_amdgcn_s_setprio(0);
    }
    __builtin_amdgcn_sched_barrier(0);
  }
#undef STAGE

#pragma unroll
  for (int mt = 0; mt < 8; ++mt) {
#pragma unroll
    for (int nt = 0; nt < 4; ++nt) {
#pragma unroll
      for (int r = 0; r < 4; ++r) {
        const long gr = row0 + wm * 128 + mt * 16 + quad * 4 + r;
        const long gc = col0 + wn * 64 + nt * 16 + l15;
        float val = acc[mt][nt][r] + bias[gc];
        if (EPI == 0) {
          int which = (int)(gc >> 9), rem = (int)gc & 511;
          int head = rem >> 6, hd = rem & 63;
          long win = gr >> 6, n = gr & 63;
          long base = (win * 8 + head) * 4096;
          unsigned short bv = f2bf(val);
          if (which == 0)      ((unsigned short*)out0)[base + n * 64 + hd] = bv;
          else if (which == 1) out1[base + n * 64 + hd] = bv;
          else                 out2[base + hd * 64 + n] = bv;   // v transposed
        } else if (EPI == 1) {
          int win = (int)(gr >> 6), n = (int)gr & 63;
          int w0 = win & 7, h0 = (win >> 3) & 7, d0 = (win >> 6) & 7, b2 = win >> 9;
          int dx = n & 3, dy = (n >> 2) & 3, dz = n >> 4;
          int od = (d0 * 4 + dz + 2) & 31, oh = (h0 * 4 + dy + 2) & 31, ow = (w0 * 4 + dx + 2) & 31;
          long addr = ((((long)b2 * 32 + od) * 32 + oh) * 32 + ow) * 512 + gc;
          ((float*)out0)[addr] = res[addr] + val;
        } else if (EPI == 2) {
          float ge = 0.5f * val * (1.0f + erf_fast(val * 0.70710678118654752f));
          ((unsigned short*)out0)[gr * 2048 + gc] = f2bf(ge);
        } else {
          long addr = gr * 512 + gc;
          ((float*)out0)[addr] = res[addr] + val;
        }
      }
    }
  }
}

// ---------------- attention: one wave per (window, head) -------------------
__global__ __launch_bounds__(256)
void attn_kernel(const unsigned short* __restrict__ q,
                 const unsigned short* __restrict__ k,
                 const unsigned short* __restrict__ vt,
                 unsigned short* __restrict__ out) {
  __shared__ unsigned short Ps[4][64 * 72];
  const int lane = threadIdx.x & 63;
  const int wave = threadIdx.x >> 6;
  const int quad = lane >> 4;
  const int l15 = lane & 15;
  const int unit = blockIdx.x * 4 + wave;
  const int win = unit >> 3;
  const int head = unit & 7;
  const long base = (long)unit * 4096;

  f32x4 s[4][4] = {};
#pragma unroll
  for (int kk = 0; kk < 64; kk += 32) {
    short8v a[4], b[4];
#pragma unroll
    for (int t = 0; t < 4; ++t) {
      a[t] = *(const short8v*)(q + base + (t * 16 + l15) * 64 + kk + quad * 8);
      b[t] = *(const short8v*)(k + base + (t * 16 + l15) * 64 + kk + quad * 8);
    }
#pragma unroll
    for (int mt = 0; mt < 4; ++mt)
#pragma unroll
      for (int nt = 0; nt < 4; ++nt)
        s[mt][nt] = __builtin_amdgcn_mfma_f32_16x16x32_bf16(a[mt], b[nt], s[mt][nt], 0, 0, 0);
  }

  float lrow[4][4];
#pragma unroll
  for (int mt = 0; mt < 4; ++mt) {
#pragma unroll
    for (int r = 0; r < 4; ++r) {
      float v0 = s[mt][0][r] * 0.125f, v1 = s[mt][1][r] * 0.125f;
      float v2 = s[mt][2][r] * 0.125f, v3 = s[mt][3][r] * 0.125f;
      float mx = fmaxf(fmaxf(v0, v1), fmaxf(v2, v3));
#pragma unroll
      for (int off = 1; off < 16; off <<= 1) mx = fmaxf(mx, __shfl_xor(mx, off, 64));
      v0 = __expf(v0 - mx); v1 = __expf(v1 - mx);
      v2 = __expf(v2 - mx); v3 = __expf(v3 - mx);
      float sm = v0 + v1 + v2 + v3;
#pragma unroll
      for (int off = 1; off < 16; off <<= 1) sm += __shfl_xor(sm, off, 64);
      lrow[mt][r] = sm;
      int row = mt * 16 + quad * 4 + r;
      Ps[wave][row * 72 + 0 + l15]  = f2bf(v0);
      Ps[wave][row * 72 + 16 + l15] = f2bf(v1);
      Ps[wave][row * 72 + 32 + l15] = f2bf(v2);
      Ps[wave][row * 72 + 48 + l15] = f2bf(v3);
    }
  }
  __syncthreads();

  f32x4 o[4][4] = {};
#pragma unroll
  for (int kk = 0; kk < 64; kk += 32) {
    short8v a[4], b[4];
#pragma unroll
    for (int t = 0; t < 4; ++t) {
      a[t] = *(const short8v*)(&Ps[wave][(t * 16 + l15) * 72 + kk + quad * 8]);
      b[t] = *(const short8v*)(vt + base + (t * 16 + l15) * 64 + kk + quad * 8);
    }
#pragma unroll
    for (int mt = 0; mt < 4; ++mt)
#pragma unroll
      for (int nt = 0; nt < 4; ++nt)
        o[mt][nt] = __builtin_amdgcn_mfma_f32_16x16x32_bf16(a[mt], b[nt], o[mt][nt], 0, 0, 0);
  }

#pragma unroll
  for (int mt = 0; mt < 4; ++mt)
#pragma unroll
    for (int nt = 0; nt < 4; ++nt)
#pragma unroll
      for (int r = 0; r < 4; ++r) {
        int row = mt * 16 + quad * 4 + r;
        int col = nt * 16 + l15;
        float val = o[mt][nt][r] / lrow[mt][r];
        out[((long)win * 64 + row) * 512 + head * 64 + col] = f2bf(val);
      }
}

// ---------------- launch ---------------------------------------------------
extern "C" void kernel_launch(void* const* d_in, const int* in_sizes, int n_in,
                              void* d_out, int out_size, void* d_ws, size_t ws_size,
                              hipStream_t stream) {
  const float* x      = (const float*)d_in[0];
  const float* ln1_g  = (const float*)d_in[1];
  const float* ln1_b  = (const float*)d_in[2];
  const float* qkv_w  = (const float*)d_in[3];
  const float* qkv_b  = (const float*)d_in[4];
  const float* proj_w = (const float*)d_in[5];
  const float* proj_b = (const float*)d_in[6];
  const float* ln2_g  = (const float*)d_in[7];
  const float* ln2_b  = (const float*)d_in[8];
  const float* w1     = (const float*)d_in[9];
  const float* b1     = (const float*)d_in[10];
  const float* w2     = (const float*)d_in[11];
  const float* b2     = (const float*)d_in[12];

  // workspace layout (bytes); hid overlays attn_out+q+k+v (dead after proj)
  char* ws = (char*)d_ws;
  unsigned short* wt_all  = (unsigned short*)ws;
  unsigned short* wt_qkv  = (unsigned short*)(ws + 0);          // 1536x512 bf16
  unsigned short* wt_proj = (unsigned short*)(ws + 1572864);    // 512x512
  unsigned short* wt_1    = (unsigned short*)(ws + 2097152);    // 2048x512
  unsigned short* wt_2    = (unsigned short*)(ws + 4194304);    // 512x2048
  float*          xo      = (float*)(ws + 8388608);             // 128 MiB fp32
  unsigned short* h       = (unsigned short*)(ws + 142606336);  // 64 MiB bf16 (h, then h2)
  unsigned short* attno   = (unsigned short*)(ws + 209715200);  // 64 MiB
  unsigned short* qb      = (unsigned short*)(ws + 276824064);  // 64 MiB
  unsigned short* kb      = (unsigned short*)(ws + 343932928);  // 64 MiB
  unsigned short* vb      = (unsigned short*)(ws + 411041792);  // 64 MiB
  unsigned short* hid     = (unsigned short*)(ws + 209715200);  // 256 MiB overlay
  float* out = (float*)d_out;

  wprep_all<<<12288, 256, 0, stream>>>(qkv_w, proj_w, w1, w2, wt_all);

  ln_kernel<<<16384, 256, 0, stream>>>(x, ln1_g, ln1_b, h, 1);
  gemm_bt<0><<<dim3(6, 256), 512, 0, stream>>>(h, wt_qkv, qkv_b, 512, qb, kb, vb, nullptr);
  attn_kernel<<<2048, 256, 0, stream>>>(qb, kb, vb, attno);
  gemm_bt<1><<<dim3(2, 256), 512, 0, stream>>>(attno, wt_proj, proj_b, 512, xo, nullptr, nullptr, x);
  ln_kernel<<<16384, 256, 0, stream>>>(xo, ln2_g, ln2_b, h, 0);
  gemm_bt<2><<<dim3(8, 256), 512, 0, stream>>>(h, wt_1, b1, 512, hid, nullptr, nullptr, nullptr);
  gemm_bt<3><<<dim3(2, 256), 512, 0, stream>>>(hid, wt_2, b2, 2048, out, nullptr, nullptr, xo);
}

// Round 7
// 985.384 us; speedup vs baseline: 1.1130x; 1.0873x over previous
//
#include <hip/hip_runtime.h>
#include <hip/hip_bf16.h>

// Windowed 3D attention transformer block, MI355X bf16-MFMA implementation.
// Residual stream fp32; GEMM/attention compute bf16 in, fp32 accumulate.
// R9: (a) QKV epilogue rewritten: acc -> LDS (output layout; v transposed via
//     packed ds_write_b64) -> 16 coalesced 8KiB region copies. Removes the
//     64-line-scatter v stores that cost ~10us/block (QKV was 39.4 vs FFN1
//     29.5 us/block with identical K-loops).
//     (b) proj+ln2 fused (gemm_ln): 128x512 full-row tiles, 3-slot ring,
//     counted vmcnt(5); epilogue does bias+residual, row-LN via shuffle +
//     LDS cross-wave table, writes xo(f32) AND h2(bf16). ln2 kernel deleted.
//     K-loop structure of gemm_bt unchanged from R8 (measured best).

typedef __attribute__((ext_vector_type(4))) short short4v;
typedef __attribute__((ext_vector_type(8))) short short8v;
typedef __attribute__((ext_vector_type(4))) float f32x4;

__device__ __forceinline__ unsigned short f2bf(float f) {
  unsigned u = __float_as_uint(f);
  u += 0x7fffu + ((u >> 16) & 1u);   // RNE; inputs finite
  return (unsigned short)(u >> 16);
}

// branch-free erf, Abramowitz-Stegun 7.1.26, |err| <= 1.5e-7
__device__ __forceinline__ float erf_fast(float x) {
  float ax = fabsf(x);
  float y = 1.0f + 0.3275911f * ax;
  float t;
  asm("v_rcp_f32 %0, %1" : "=v"(t) : "v"(y));
  float p = t * (0.254829592f +
            t * (-0.284496736f +
            t * (1.421413741f +
            t * (-1.453152027f +
            t * 1.061405429f))));
  float e = __expf(-ax * ax);
  float r = 1.0f - p * e;
  return copysignf(r, x);
}

// async 16B global->LDS DMA; LDS dest = wave-uniform base + lane*16
__device__ __forceinline__ void gload_lds16(const unsigned short* g, unsigned short* l) {
  __builtin_amdgcn_global_load_lds(
      (const __attribute__((address_space(1))) unsigned int*)g,
      (__attribute__((address_space(3))) unsigned int*)l, 16, 0, 0);
}

// ---------------- weight prep (all 4 weights, one launch) ------------------
__global__ __launch_bounds__(256)
void wprep_all(const float* __restrict__ qkv_w, const float* __restrict__ proj_w,
               const float* __restrict__ w1, const float* __restrict__ w2,
               unsigned short* __restrict__ wt) {
  int idx = blockIdx.x * 256 + threadIdx.x;
  const float* w; int kbits, N, base;
  if (idx < 786432)       { w = qkv_w;  kbits = 9;  N = 1536; base = 0; }
  else if (idx < 1048576) { w = proj_w; kbits = 9;  N = 512;  base = 786432; }
  else if (idx < 2097152) { w = w1;     kbits = 9;  N = 2048; base = 1048576; }
  else                    { w = w2;     kbits = 11; N = 512;  base = 2097152; }
  int li = idx - base;
  int K = 1 << kbits;
  int n = li >> kbits, kk = li & (K - 1);
  wt[idx] = f2bf(w[(long)kk * N + n]);
}

// ---------------- LayerNorm (one wave per 512-elem row) --------------------
__global__ __launch_bounds__(256)
void ln_kernel(const float* __restrict__ src, const float* __restrict__ g,
               const float* __restrict__ bb, unsigned short* __restrict__ dst,
               const int gather) {
  const int lane = threadIdx.x & 63;
  const int row = blockIdx.x * 4 + (threadIdx.x >> 6);
  long srow;
  if (gather) {
    int n = row & 63, win = row >> 6;
    int w0 = win & 7, h0 = (win >> 3) & 7, d0 = (win >> 6) & 7, b2 = win >> 9;
    int dx = n & 3, dy = (n >> 2) & 3, dz = n >> 4;
    int od = (d0 * 4 + dz + 2) & 31, oh = (h0 * 4 + dy + 2) & 31, ow = (w0 * 4 + dx + 2) & 31;
    srow = (((long)b2 * 32 + od) * 32 + oh) * 32 + ow;
  } else {
    srow = row;
  }
  const float4* sp = (const float4*)(src + srow * 512);
  float4 x0 = sp[lane], x1 = sp[lane + 64];
  float sum = x0.x + x0.y + x0.z + x0.w + x1.x + x1.y + x1.z + x1.w;
  float sq  = x0.x*x0.x + x0.y*x0.y + x0.z*x0.z + x0.w*x0.w
            + x1.x*x1.x + x1.y*x1.y + x1.z*x1.z + x1.w*x1.w;
#pragma unroll
  for (int off = 1; off < 64; off <<= 1) {
    sum += __shfl_xor(sum, off, 64);
    sq  += __shfl_xor(sq, off, 64);
  }
  float mean = sum * (1.0f / 512.0f);
  float var  = sq * (1.0f / 512.0f) - mean * mean;
  float rstd = rsqrtf(var + 1e-5f);
  float4 g0 = ((const float4*)g)[lane], g1 = ((const float4*)g)[lane + 64];
  float4 b0 = ((const float4*)bb)[lane], b1v = ((const float4*)bb)[lane + 64];
  ushort4 o0, o1;
  o0.x = f2bf((x0.x - mean) * rstd * g0.x + b0.x);
  o0.y = f2bf((x0.y - mean) * rstd * g0.y + b0.y);
  o0.z = f2bf((x0.z - mean) * rstd * g0.z + b0.z);
  o0.w = f2bf((x0.w - mean) * rstd * g0.w + b0.w);
  o1.x = f2bf((x1.x - mean) * rstd * g1.x + b1v.x);
  o1.y = f2bf((x1.y - mean) * rstd * g1.y + b1v.y);
  o1.z = f2bf((x1.z - mean) * rstd * g1.z + b1v.z);
  o1.w = f2bf((x1.w - mean) * rstd * g1.w + b1v.w);
  *(ushort4*)(dst + (long)row * 512 + lane * 4) = o0;
  *(ushort4*)(dst + (long)row * 512 + 256 + lane * 4) = o1;
}

// ---------------- GEMM: C[M,N] = A[M,K](bf16) * Bt[N,K]^T + bias ----------
// 256x256 tile, 8 waves, K=32 sub-tiles, 4-slot LDS ring, counted vmcnt(8).
// (K-loop structure identical to R8 — measured best.)
template <int EPI>
__global__ __launch_bounds__(512, 2)
void gemm_bt(const unsigned short* __restrict__ A,
             const unsigned short* __restrict__ Bt,
             const float* __restrict__ bias, int K,
             void* __restrict__ out0,
             unsigned short* __restrict__ out1,
             unsigned short* __restrict__ out2,
             const float* __restrict__ res) {
  __shared__ unsigned short SB[4][2][8192];   // 4 ring slots x {A,B} x 256x32
  const int tid = threadIdx.x;
  const int lane = tid & 63;
  const int wv = tid >> 6;           // 0..7
  const int wm = wv >> 2;            // 0..1  (M half)
  const int wn = wv & 3;             // 0..3  (N quarter)
  const int quad = lane >> 4;
  const int l15 = lane & 15;

  // T1: bijective XCD swizzle (all grids are multiples of 8 blocks)
  const int gx = gridDim.x;
  const int nwg = gx * gridDim.y;
  const int bid = blockIdx.y * gx + blockIdx.x;
  const int cpx = nwg >> 3;
  const int wg2 = (bid & 7) * cpx + (bid >> 3);
  const int bx = wg2 % gx;
  const int by = wg2 / gx;
  const long row0 = (long)by * 256;
  const long col0 = (long)bx * 256;

  f32x4 acc[8][4] = {};

  const int srow = wv * 16 + (lane >> 2);
  const int scg  = (lane & 3) ^ ((lane >> 3) & 3);
  const unsigned short* gA0 = A  + (row0 + srow) * K + scg * 8;
  const unsigned short* gB0 = Bt + (col0 + srow) * K + scg * 8;
  const long j1 = 128L * K;
  const int lds0 = srow * 32 + (lane & 3) * 8;

#define STAGE(v) do {                                              \
    const int q_ = (v) & 3; const long ko_ = (long)(v) * 32;       \
    gload_lds16(gA0 + ko_,      &SB[q_][0][lds0]);                 \
    gload_lds16(gA0 + ko_ + j1, &SB[q_][0][lds0 + 4096]);          \
    gload_lds16(gB0 + ko_,      &SB[q_][1][lds0]);                 \
    gload_lds16(gB0 + ko_ + j1, &SB[q_][1][lds0 + 4096]);          \
  } while (0)

  const int slot = (quad ^ ((l15 >> 1) & 3)) * 8;
  const int aoff = (wm * 128 + l15) * 32 + slot;
  const int boff = (wn * 64  + l15) * 32 + slot;

  const int nsub = K >> 5;
  STAGE(0); STAGE(1); STAGE(2);

  for (int u = 0; u < nsub; ++u) {
    if (u < nsub - 2)       asm volatile("s_waitcnt vmcnt(8)" ::: "memory");
    else if (u == nsub - 2) asm volatile("s_waitcnt vmcnt(4)" ::: "memory");
    else                    asm volatile("s_waitcnt vmcnt(0)" ::: "memory");
    __builtin_amdgcn_s_barrier();
    __builtin_amdgcn_sched_barrier(0);
    if (u + 3 < nsub) STAGE(u + 3);

    const unsigned short* Au = &SB[u & 3][0][0];
    const unsigned short* Bu = &SB[u & 3][1][0];
    short8v bf[4];
#pragma unroll
    for (int nt = 0; nt < 4; ++nt) bf[nt] = *(const short8v*)&Bu[boff + nt * 512];
#pragma unroll
    for (int mh = 0; mh < 2; ++mh) {
      short8v af[4];
#pragma unroll
      for (int i = 0; i < 4; ++i) af[i] = *(const short8v*)&Au[aoff + (mh * 4 + i) * 512];
      __builtin_amdgcn_s_setprio(1);
#pragma unroll
      for (int i = 0; i < 4; ++i)
#pragma unroll
        for (int nt = 0; nt < 4; ++nt)
          acc[mh * 4 + i][nt] = __builtin_amdgcn_mfma_f32_16x16x32_bf16(
              af[i], bf[nt], acc[mh * 4 + i][nt], 0, 0, 0);
      __builtin_amdgcn_s_setprio(0);
    }
    __builtin_amdgcn_sched_barrier(0);
  }
#undef STAGE

  if (EPI == 0) {
    // ---- QKV epilogue: repack through LDS, then coalesced region copies.
    // Block is purely q, k, or v: which = col0>>9, head0 = (col0&511)>>6.
    const int which = (int)(col0 >> 9);
    const int head0 = ((int)col0 & 511) >> 6;
    const int win0  = (int)(row0 >> 6);
    unsigned short* OUT = (which == 0) ? (unsigned short*)out0
                        : (which == 1) ? out1 : out2;
    unsigned short* SBu = &SB[0][0][0];        // 65536 ushorts = full tile
    __syncthreads();                           // K-loop LDS reads all consumed
    if (which < 2) {                           // q/k: [n][hd] per (win,head)
#pragma unroll
      for (int mt = 0; mt < 8; ++mt) {
        const int grl = wm * 128 + mt * 16 + quad * 4;
#pragma unroll
        for (int nt = 0; nt < 4; ++nt) {
          const int col = nt * 16 + l15;
          const float bv = bias[col0 + wn * 64 + col];
#pragma unroll
          for (int r = 0; r < 4; ++r) {
            const int row = grl + r;
            SBu[((row >> 6) * 4 + wn) * 4096 + (row & 63) * 64 + col] =
                f2bf(acc[mt][nt][r] + bv);
          }
        }
      }
    } else {                                   // v: [hd][n] (transposed)
#pragma unroll
      for (int mt = 0; mt < 8; ++mt) {
        const int grl = wm * 128 + mt * 16 + quad * 4;
#pragma unroll
        for (int nt = 0; nt < 4; ++nt) {
          const int col = nt * 16 + l15;
          const float bv = bias[col0 + wn * 64 + col];
          ushort4 pk;
          pk.x = f2bf(acc[mt][nt][0] + bv);
          pk.y = f2bf(acc[mt][nt][1] + bv);
          pk.z = f2bf(acc[mt][nt][2] + bv);
          pk.w = f2bf(acc[mt][nt][3] + bv);
          *(ushort4*)&SBu[((grl >> 6) * 4 + wn) * 4096 + col * 64 + (grl & 63)] = pk;
        }
      }
    }
    __syncthreads();
#pragma unroll
    for (int it = 0; it < 16; ++it) {          // 16 disjoint 8KiB regions
      unsigned short* dst = OUT +
          ((long)((win0 + (it >> 2)) * 8 + head0 + (it & 3))) * 4096 + tid * 8;
      *(short8v*)dst = *(const short8v*)&SBu[it * 4096 + tid * 8];
    }
    return;
  }

#pragma unroll
  for (int mt = 0; mt < 8; ++mt) {
#pragma unroll
    for (int nt = 0; nt < 4; ++nt) {
#pragma unroll
      for (int r = 0; r < 4; ++r) {
        const long gr = row0 + wm * 128 + mt * 16 + quad * 4 + r;
        const long gc = col0 + wn * 64 + nt * 16 + l15;
        float val = acc[mt][nt][r] + bias[gc];
        if (EPI == 2) {
          float ge = 0.5f * val * (1.0f + erf_fast(val * 0.70710678118654752f));
          ((unsigned short*)out0)[gr * 2048 + gc] = f2bf(ge);
        } else {
          long addr = gr * 512 + gc;
          ((float*)out0)[addr] = res[addr] + val;
        }
      }
    }
  }
}

// ---------------- proj GEMM + residual + LayerNorm (fused) ----------------
// C[65536,512] = A[65536,512] * Bt[512,512]^T + bias; xo = res + C (spatial
// scatter); h2 = LN(xo) * g2 + b2. Block = 128 rows x 512 cols (full rows ->
// row stats local to block). 8 waves (2M x 4N), wave = 64x128, acc 4x8.
// 3-slot LDS ring, K=32 subs, 5 loads/thread/sub (1 A + 4 B), vmcnt(5).
__global__ __launch_bounds__(512, 2)
void gemm_ln(const unsigned short* __restrict__ A,
             const unsigned short* __restrict__ Bt,
             const float* __restrict__ bias,
             const float* __restrict__ res,
             const float* __restrict__ g2, const float* __restrict__ b2v,
             float* __restrict__ xo, unsigned short* __restrict__ h2) {
  __shared__ unsigned short SB[3][20480];      // per slot: A 4096 | B 16384
  const int tid = threadIdx.x;
  const int lane = tid & 63;
  const int wv = tid >> 6;
  const int wm = wv >> 2;            // 0..1
  const int wn = wv & 3;             // 0..3
  const int quad = lane >> 4;
  const int l15 = lane & 15;

  const int bid = blockIdx.x;                  // 512 blocks
  const int by = (bid & 7) * 64 + (bid >> 3);  // XCD swizzle (512 % 8 == 0)
  const long row0 = (long)by * 128;

  f32x4 acc[4][8] = {};

  const int srow = wv * 16 + (lane >> 2);      // 0..127
  const int scg  = (lane & 3) ^ ((lane >> 3) & 3);
  const unsigned short* gA0 = A  + (row0 + srow) * 512 + scg * 8;
  const unsigned short* gB0 = Bt + srow * 512 + scg * 8;
  const int lds0 = srow * 32 + (lane & 3) * 8;

#define STAGEL(v) do {                                             \
    unsigned short* s_ = &SB[(v) % 3][0];                          \
    const long ko_ = (long)(v) * 32;                               \
    gload_lds16(gA0 + ko_,               &s_[lds0]);               \
    gload_lds16(gB0 + ko_,               &s_[4096  + lds0]);       \
    gload_lds16(gB0 + ko_ + 128L * 512,  &s_[8192  + lds0]);       \
    gload_lds16(gB0 + ko_ + 256L * 512,  &s_[12288 + lds0]);       \
    gload_lds16(gB0 + ko_ + 384L * 512,  &s_[16384 + lds0]);       \
  } while (0)

  const int slot = (quad ^ ((l15 >> 1) & 3)) * 8;
  const int aoff = (wm * 64 + l15) * 32 + slot;
  const int boff = 4096 + (wn * 128 + l15) * 32 + slot;

  STAGEL(0); STAGEL(1);                        // 2 subs in flight (10 loads)

  for (int u = 0; u < 16; ++u) {
    if (u < 15) asm volatile("s_waitcnt vmcnt(5)" ::: "memory");
    else        asm volatile("s_waitcnt vmcnt(0)" ::: "memory");
    __builtin_amdgcn_s_barrier();
    __builtin_amdgcn_sched_barrier(0);
    if (u + 2 < 16) STAGEL(u + 2);             // slot (u+2)%3 == (u-1)%3

    const unsigned short* Su = &SB[u % 3][0];
    short8v af[4], bf[8];
#pragma unroll
    for (int i = 0; i < 4; ++i)  af[i] = *(const short8v*)&Su[aoff + i * 512];
#pragma unroll
    for (int nt = 0; nt < 8; ++nt) bf[nt] = *(const short8v*)&Su[boff + nt * 512];
    __builtin_amdgcn_s_setprio(1);
#pragma unroll
    for (int i = 0; i < 4; ++i)
#pragma unroll
      for (int nt = 0; nt < 8; ++nt)
        acc[i][nt] = __builtin_amdgcn_mfma_f32_16x16x32_bf16(
            af[i], bf[nt], acc[i][nt], 0, 0, 0);
    __builtin_amdgcn_s_setprio(0);
    __builtin_amdgcn_sched_barrier(0);
  }
#undef STAGEL

  // ---- epilogue: bias + residual; row-LN; write xo (f32) + h2 (bf16) ----
  __syncthreads();                             // all K-loop reads consumed
  float* part = (float*)&SB[0][0];             // [128 rows][4 wn][2] floats

#pragma unroll
  for (int mt = 0; mt < 4; ++mt) {
#pragma unroll
    for (int r = 0; r < 4; ++r) {
      const int gr = (int)row0 + wm * 64 + mt * 16 + quad * 4 + r;
      const int win = gr >> 6, n = gr & 63;
      const int w0 = win & 7, h0 = (win >> 3) & 7, d0 = (win >> 6) & 7, b2i = win >> 9;
      const int dx = n & 3, dy = (n >> 2) & 3, dz = n >> 4;
      const int od = (d0 * 4 + dz + 2) & 31, oh = (h0 * 4 + dy + 2) & 31, ow = (w0 * 4 + dx + 2) & 31;
      const long sp = (((long)b2i * 32 + od) * 32 + oh) * 32 + ow;
      float s = 0.f, q = 0.f;
#pragma unroll
      for (int nt = 0; nt < 8; ++nt) {
        const int gc = wn * 128 + nt * 16 + l15;
        float v = acc[mt][nt][r] + bias[gc] + res[sp * 512 + gc];
        acc[mt][nt][r] = v;
        s += v; q += v * v;
      }
#pragma unroll
      for (int off = 1; off < 16; off <<= 1) {
        s += __shfl_xor(s, off, 64);
        q += __shfl_xor(q, off, 64);
      }
      if (l15 == 0) {
        const int rowl = wm * 64 + mt * 16 + quad * 4 + r;
        *(float2*)&part[(rowl * 4 + wn) * 2] = make_float2(s, q);
      }
    }
  }
  __syncthreads();

#pragma unroll
  for (int mt = 0; mt < 4; ++mt) {
#pragma unroll
    for (int r = 0; r < 4; ++r) {
      const int rowl = wm * 64 + mt * 16 + quad * 4 + r;
      const float4 p0 = *(const float4*)&part[rowl * 8];
      const float4 p1 = *(const float4*)&part[rowl * 8 + 4];
      const float s = p0.x + p0.z + p1.x + p1.z;
      const float q = p0.y + p0.w + p1.y + p1.w;
      const float mean = s * (1.0f / 512.0f);
      const float rstd = rsqrtf(q * (1.0f / 512.0f) - mean * mean + 1e-5f);
      const int gr = (int)row0 + rowl;
      const int win = gr >> 6, n = gr & 63;
      const int w0 = win & 7, h0 = (win >> 3) & 7, d0 = (win >> 6) & 7, b2i = win >> 9;
      const int dx = n & 3, dy = (n >> 2) & 3, dz = n >> 4;
      const int od = (d0 * 4 + dz + 2) & 31, oh = (h0 * 4 + dy + 2) & 31, ow = (w0 * 4 + dx + 2) & 31;
      const long sp = (((long)b2i * 32 + od) * 32 + oh) * 32 + ow;
#pragma unroll
      for (int nt = 0; nt < 8; ++nt) {
        const int gc = wn * 128 + nt * 16 + l15;
        const float v = acc[mt][nt][r];
        xo[sp * 512 + gc] = v;
        h2[sp * 512 + gc] = f2bf((v - mean) * rstd * g2[gc] + b2v[gc]);
      }
    }
  }
}

// ---------------- attention: one wave per (window, head) -------------------
__global__ __launch_bounds__(256)
void attn_kernel(const unsigned short* __restrict__ q,
                 const unsigned short* __restrict__ k,
                 const unsigned short* __restrict__ vt,
                 unsigned short* __restrict__ out) {
  __shared__ unsigned short Ps[4][64 * 72];
  const int lane = threadIdx.x & 63;
  const int wave = threadIdx.x >> 6;
  const int quad = lane >> 4;
  const int l15 = lane & 15;
  const int unit = blockIdx.x * 4 + wave;
  const int win = unit >> 3;
  const int head = unit & 7;
  const long base = (long)unit * 4096;

  f32x4 s[4][4] = {};
#pragma unroll
  for (int kk = 0; kk < 64; kk += 32) {
    short8v a[4], b[4];
#pragma unroll
    for (int t = 0; t < 4; ++t) {
      a[t] = *(const short8v*)(q + base + (t * 16 + l15) * 64 + kk + quad * 8);
      b[t] = *(const short8v*)(k + base + (t * 16 + l15) * 64 + kk + quad * 8);
    }
#pragma unroll
    for (int mt = 0; mt < 4; ++mt)
#pragma unroll
      for (int nt = 0; nt < 4; ++nt)
        s[mt][nt] = __builtin_amdgcn_mfma_f32_16x16x32_bf16(a[mt], b[nt], s[mt][nt], 0, 0, 0);
  }

  float lrow[4][4];
#pragma unroll
  for (int mt = 0; mt < 4; ++mt) {
#pragma unroll
    for (int r = 0; r < 4; ++r) {
      float v0 = s[mt][0][r] * 0.125f, v1 = s[mt][1][r] * 0.125f;
      float v2 = s[mt][2][r] * 0.125f, v3 = s[mt][3][r] * 0.125f;
      float mx = fmaxf(fmaxf(v0, v1), fmaxf(v2, v3));
#pragma unroll
      for (int off = 1; off < 16; off <<= 1) mx = fmaxf(mx, __shfl_xor(mx, off, 64));
      v0 = __expf(v0 - mx); v1 = __expf(v1 - mx);
      v2 = __expf(v2 - mx); v3 = __expf(v3 - mx);
      float sm = v0 + v1 + v2 + v3;
#pragma unroll
      for (int off = 1; off < 16; off <<= 1) sm += __shfl_xor(sm, off, 64);
      lrow[mt][r] = sm;
      int row = mt * 16 + quad * 4 + r;
      Ps[wave][row * 72 + 0 + l15]  = f2bf(v0);
      Ps[wave][row * 72 + 16 + l15] = f2bf(v1);
      Ps[wave][row * 72 + 32 + l15] = f2bf(v2);
      Ps[wave][row * 72 + 48 + l15] = f2bf(v3);
    }
  }
  __syncthreads();

  f32x4 o[4][4] = {};
#pragma unroll
  for (int kk = 0; kk < 64; kk += 32) {
    short8v a[4], b[4];
#pragma unroll
    for (int t = 0; t < 4; ++t) {
      a[t] = *(const short8v*)(&Ps[wave][(t * 16 + l15) * 72 + kk + quad * 8]);
      b[t] = *(const short8v*)(vt + base + (t * 16 + l15) * 64 + kk + quad * 8);
    }
#pragma unroll
    for (int mt = 0; mt < 4; ++mt)
#pragma unroll
      for (int nt = 0; nt < 4; ++nt)
        o[mt][nt] = __builtin_amdgcn_mfma_f32_16x16x32_bf16(a[mt], b[nt], o[mt][nt], 0, 0, 0);
  }

#pragma unroll
  for (int mt = 0; mt < 4; ++mt)
#pragma unroll
    for (int nt = 0; nt < 4; ++nt)
#pragma unroll
      for (int r = 0; r < 4; ++r) {
        int row = mt * 16 + quad * 4 + r;
        int col = nt * 16 + l15;
        float val = o[mt][nt][r] / lrow[mt][r];
        out[((long)win * 64 + row) * 512 + head * 64 + col] = f2bf(val);
      }
}

// ---------------- launch ---------------------------------------------------
extern "C" void kernel_launch(void* const* d_in, const int* in_sizes, int n_in,
                              void* d_out, int out_size, void* d_ws, size_t ws_size,
                              hipStream_t stream) {
  const float* x      = (const float*)d_in[0];
  const float* ln1_g  = (const float*)d_in[1];
  const float* ln1_b  = (const float*)d_in[2];
  const float* qkv_w  = (const float*)d_in[3];
  const float* qkv_b  = (const float*)d_in[4];
  const float* proj_w = (const float*)d_in[5];
  const float* proj_b = (const float*)d_in[6];
  const float* ln2_g  = (const float*)d_in[7];
  const float* ln2_b  = (const float*)d_in[8];
  const float* w1     = (const float*)d_in[9];
  const float* b1     = (const float*)d_in[10];
  const float* w2     = (const float*)d_in[11];
  const float* b2     = (const float*)d_in[12];

  // workspace layout (bytes); hid overlays attn_out+q+k+v (dead after proj)
  char* ws = (char*)d_ws;
  unsigned short* wt_all  = (unsigned short*)ws;
  unsigned short* wt_qkv  = (unsigned short*)(ws + 0);          // 1536x512 bf16
  unsigned short* wt_proj = (unsigned short*)(ws + 1572864);    // 512x512
  unsigned short* wt_1    = (unsigned short*)(ws + 2097152);    // 2048x512
  unsigned short* wt_2    = (unsigned short*)(ws + 4194304);    // 512x2048
  float*          xo      = (float*)(ws + 8388608);             // 128 MiB fp32
  unsigned short* h       = (unsigned short*)(ws + 142606336);  // 64 MiB bf16 (h, then h2)
  unsigned short* attno   = (unsigned short*)(ws + 209715200);  // 64 MiB
  unsigned short* qb      = (unsigned short*)(ws + 276824064);  // 64 MiB
  unsigned short* kb      = (unsigned short*)(ws + 343932928);  // 64 MiB
  unsigned short* vb      = (unsigned short*)(ws + 411041792);  // 64 MiB
  unsigned short* hid     = (unsigned short*)(ws + 209715200);  // 256 MiB overlay
  float* out = (float*)d_out;

  wprep_all<<<12288, 256, 0, stream>>>(qkv_w, proj_w, w1, w2, wt_all);

  ln_kernel<<<16384, 256, 0, stream>>>(x, ln1_g, ln1_b, h, 1);
  gemm_bt<0><<<dim3(6, 256), 512, 0, stream>>>(h, wt_qkv, qkv_b, 512, qb, kb, vb, nullptr);
  attn_kernel<<<2048, 256, 0, stream>>>(qb, kb, vb, attno);
  gemm_ln<<<512, 512, 0, stream>>>(attno, wt_proj, proj_b, x, ln2_g, ln2_b, xo, h);
  gemm_bt<2><<<dim3(8, 256), 512, 0, stream>>>(h, wt_1, b1, 512, hid, nullptr, nullptr, nullptr);
  gemm_bt<3><<<dim3(2, 256), 512, 0, stream>>>(hid, wt_2, b2, 2048, out, nullptr, nullptr, xo);
}